// Round 14
// baseline (159.988 us; speedup 1.0000x reference)
//
#include <hip/hip_runtime.h>
#include <math.h>

// RecurNN: B=256, L=256, E=100, T=255.
// x_t = W1L*left_t + W1R*right_t + b1; h_t = tanh(x_t); out = sigmoid(W2 h_254 + b2).
// These inputs: right_t always a leaf; left_t = node t-1 (leaf only at t=0).
//
// R14: 512 thr = 8 waves, one block per batch row.
//  waves 0,1 (consumers): lane l owns row e=50*wv+l; W1L row in 100 named scalar
//    VGPRs. Hybrid broadcast: k=0..63 via 16 UNIFORM ds_read_b128 quads (VGPR
//    fmas, no SGPR hazards), k=64..99 via 36 v_readlane (vh/vo). Splits the
//    dot across DS and VALU pipes (R13 measured: 200 rl+fma = ~1200 cyc/wave).
//  waves 2..7 (producers, 3 pairs): pair p builds c[t] for t ≡ p (mod 3) SPREAD
//    OVER 3 TICKS (k-chunks 0-31/32-67/68-99), emb loads issued 3 ticks (~2000
//    cyc) ahead -> producers permanently off the critical path. c[0..2] built
//    in a one-time prologue.
//  Sync: one "s_waitcnt lgkmcnt(0); s_barrier" per tick; vmcnt never drained.

#define Bc 256
#define Lc 256
#define Ec 100
#define Tc 255
#define W1cols 200

#define RL(v, k) __int_as_float(__builtin_amdgcn_readlane(__float_as_int(v), (k)))

#define REP100(X) \
 X(0) X(1) X(2) X(3) X(4) X(5) X(6) X(7) X(8) X(9) X(10) X(11) X(12) X(13) X(14) X(15) \
 X(16) X(17) X(18) X(19) X(20) X(21) X(22) X(23) X(24) X(25) X(26) X(27) X(28) X(29) X(30) X(31) \
 X(32) X(33) X(34) X(35) X(36) X(37) X(38) X(39) X(40) X(41) X(42) X(43) X(44) X(45) X(46) X(47) \
 X(48) X(49) X(50) X(51) X(52) X(53) X(54) X(55) X(56) X(57) X(58) X(59) X(60) X(61) X(62) X(63) \
 X(64) X(65) X(66) X(67) X(68) X(69) X(70) X(71) X(72) X(73) X(74) X(75) X(76) X(77) X(78) X(79) \
 X(80) X(81) X(82) X(83) X(84) X(85) X(86) X(87) X(88) X(89) X(90) X(91) X(92) X(93) X(94) X(95) \
 X(96) X(97) X(98) X(99)

#define DECLW(k) float w##k;

// selectors (k literal; ternaries fold)
#define SRC0(k) RL((k) < 50 ? vh : vo, (k) < 50 ? (k) : (k) - 50)   // consumer wave 0
#define SRC1(k) RL((k) < 50 ? vo : vh, (k) < 50 ? (k) : (k) - 50)   // consumer wave 1
#define SRCP(k) RL((k) < 64 ? vA : vB, (k) < 64 ? (k) : (k) - 64)   // producer

#define G8(S,a,b,c,d,e,f,g,h2) { \
    const float r0_=S(a), r1_=S(b), r2_=S(c), r3_=S(d), \
                r4_=S(e), r5_=S(f), r6_=S(g), r7_=S(h2); \
    acc0 = fmaf(r0_, w##a, acc0); acc1 = fmaf(r1_, w##b, acc1); \
    acc2 = fmaf(r2_, w##c, acc2); acc3 = fmaf(r3_, w##d, acc3); \
    acc0 = fmaf(r4_, w##e, acc0); acc1 = fmaf(r5_, w##f, acc1); \
    acc2 = fmaf(r6_, w##g, acc2); acc3 = fmaf(r7_, w##h2, acc3); }
#define G4(S,a,b,c,d) { \
    const float r0_=S(a), r1_=S(b), r2_=S(c), r3_=S(d); \
    acc0 = fmaf(r0_, w##a, acc0); acc1 = fmaf(r1_, w##b, acc1); \
    acc2 = fmaf(r2_, w##c, acc2); acc3 = fmaf(r3_, w##d, acc3); }

// producer k-chunks (one per tick)
#define CHUNK0(S) G8(S,0,1,2,3,4,5,6,7) G8(S,8,9,10,11,12,13,14,15) \
                  G8(S,16,17,18,19,20,21,22,23) G8(S,24,25,26,27,28,29,30,31)
#define CHUNK1(S) G8(S,32,33,34,35,36,37,38,39) G8(S,40,41,42,43,44,45,46,47) \
                  G8(S,48,49,50,51,52,53,54,55) G8(S,56,57,58,59,60,61,62,63) \
                  G4(S,64,65,66,67)
#define CHUNK2(S) G8(S,68,69,70,71,72,73,74,75) G8(S,76,77,78,79,80,81,82,83) \
                  G8(S,84,85,86,87,88,89,90,91) G8(S,92,93,94,95,96,97,98,99)

// consumer readlane tail k=64..99
#define RLPART(S) G8(S,64,65,66,67,68,69,70,71) G8(S,72,73,74,75,76,77,78,79) \
                  G8(S,80,81,82,83,84,85,86,87) G8(S,88,89,90,91,92,93,94,95) \
                  G4(S,96,97,98,99)

// consumer quad fma (VGPR x VGPR, no SGPRs)
#define QFMA(Q,a,b,c,d) { acc0 = fmaf(Q.x, w##a, acc0); acc1 = fmaf(Q.y, w##b, acc1); \
                          acc2 = fmaf(Q.z, w##c, acc2); acc3 = fmaf(Q.w, w##d, acc3); }

// generic fallback dot (weights from global; never hot for these inputs)
__device__ __noinline__ float slow_dot(const float* rp, const float* wr) {
    float a0 = 0.f, a1 = 0.f, a2 = 0.f, a3 = 0.f;
    for (int qq = 0; qq < 25; ++qq) {
        float4 h4 = *(const float4*)(rp + 4 * qq);
        float4 w4 = *(const float4*)(wr + 4 * qq);
        a0 = fmaf(w4.x, h4.x, a0); a1 = fmaf(w4.y, h4.y, a1);
        a2 = fmaf(w4.z, h4.z, a2); a3 = fmaf(w4.w, h4.w, a3);
    }
    return (a0 + a1) + (a2 + a3);
}

__global__ __launch_bounds__(512, 2)
void fused(const int* __restrict__ token_ids,
           const int* __restrict__ comp_left,
           const int* __restrict__ comp_right,
           const float* __restrict__ emb,
           const float* __restrict__ W1,
           const float* __restrict__ b1,
           const float* __restrict__ W2,
           const float* __restrict__ b2,
           float* __restrict__ out)
{
    const int b    = blockIdx.x;
    const int tid  = threadIdx.x;          // 0..511
    const int wv   = tid >> 6;             // 0,1 consumers; 2..7 producers
    const int l    = tid & 63;
    const bool cons = (wv < 2);
    const int lc   = (l < 50) ? l : 49;

    __shared__ __align__(16) float hist[Tc * Ec];   // 102000 B (zero = unwritten)
    __shared__ float cring[4][Ec];                  // c ring
    __shared__ int2  ccS[Tc];
    __shared__ int   tokRS[Tc], tokLS[Tc];          // leaf tokens (-1 = internal)
    __shared__ float red[2];

    // ---- prologue staging ----
    for (int i = tid; i < Tc; i += 512) {
        const int cl = comp_left [b * Tc + i];
        const int cr = comp_right[b * Tc + i];
        ccS[i]   = make_int2(cl, cr);
        tokRS[i] = (cr < Lc) ? token_ids[b * Lc + cr] : -1;
        tokLS[i] = (cl < Lc) ? token_ids[b * Lc + cl] : -1;
    }
    {   const float4 z4 = make_float4(0.f, 0.f, 0.f, 0.f);
        for (int i = tid; i < (Tc * Ec) / 4; i += 512) ((float4*)hist)[i] = z4;
    }

    // ---- role weights: consumer W1L row; producer W1R row (pair-half rows) ----
    const int prow = 50 * ((wv - 2) & 1) + lc;            // producer row (waves 2..7)
    const int erow = cons ? (50 * wv + lc) : prow;
    const float* wrow = W1 + (size_t)erow * W1cols + (cons ? 0 : Ec);
    REP100(DECLW)
#define LOADW(k) w##k = wrow[k];
    REP100(LOADW)
#undef LOADW
    const float b1e = b1[erow];
    const float w2e = W2[erow];
    const float b2v = b2[0];

    __syncthreads();   // staging + weights visible

    // ---- persistent state ----
    float vh = 0.f;                        // consumer: own h value (lanes 0-49)
    int2  cc = make_int2(0, 0);
    float pvA = 0.f, pvB = 0.f;            // producer: row being consumed (3-tick window)
    float nA = 0.f, nB = 0.f;              // producer: row in flight
    float acc0 = 0.f, acc1 = 0.f, acc2 = 0.f, acc3 = 0.f;   // producer accs (persist)
    int   tcur = 0, phc = 0;

    if (cons) {
        cc = ccS[0];
    } else {
        // ---- producer prologue: pair p computes c[p] fully; issue loads for p+3 ----
        const int p = (wv - 2) >> 1;
        tcur = p + 3;
        phc  = -p;
        const int tk0 = __builtin_amdgcn_readfirstlane(tokRS[p]);
        float pA = 0.f, pB = 0.f;
        if (tk0 >= 0) {
            const float* g = emb + (size_t)tk0 * Ec;
            pA = g[l];
            if (l < 36) pB = g[64 + l];
        }
        acc0 = b1e;
        { const float vA = pA, vB = pB; CHUNK0(SRCP) CHUNK1(SRCP) CHUNK2(SRCP) }
        if (l < 50) cring[p & 3][erow] = (acc0 + acc1) + (acc2 + acc3);
        const int tk3 = (p + 3 < Tc) ? __builtin_amdgcn_readfirstlane(tokRS[p + 3]) : -1;
        if (tk3 >= 0) {
            const float* g = emb + (size_t)tk3 * Ec;
            nA = g[l];
            nB = (l < 36) ? g[64 + l] : 0.f;
        } else { nA = 0.f; nB = 0.f; }
    }

    // ---- main loop: tick i; consumer does t=i-1; producers build ahead ----
    #pragma unroll 1
    for (int i = 0; i <= Tc; ++i) {
        if (!cons) {
            // ================= PRODUCER (3-tick window per c) =================
            if (phc >= 0 && tcur < Tc) {
                if (phc == 0) {
                    pvA = nA; pvB = nB;            // loads issued 3 ticks ago
                    acc0 = b1e; acc1 = 0.f; acc2 = 0.f; acc3 = 0.f;
                    const int tnx = tcur + 3;      // issue next window's loads
                    const int tk = (tnx < Tc) ? __builtin_amdgcn_readfirstlane(tokRS[tnx]) : -1;
                    if (tk >= 0) {
                        const float* g = emb + (size_t)tk * Ec;
                        nA = g[l];
                        nB = (l < 36) ? g[64 + l] : 0.f;
                    } else { nA = 0.f; nB = 0.f; }
                    { const float vA = pvA, vB = pvB; CHUNK0(SRCP) }
                } else if (phc == 1) {
                    { const float vA = pvA, vB = pvB; CHUNK1(SRCP) }
                } else {
                    { const float vA = pvA, vB = pvB; CHUNK2(SRCP) }
                    if (l < 50) cring[tcur & 3][erow] = (acc0 + acc1) + (acc2 + acc3);
                    tcur += 3;
                }
            }
            phc = (phc >= 2) ? 0 : phc + 1;
        } else {
            // ================= CONSUMER =================
            const int tc = i - 1;
            if (tc >= 0) {
                const int li = __builtin_amdgcn_readfirstlane(cc.x);
                const int ri = __builtin_amdgcn_readfirstlane(cc.y);
                const int2 ccn = (tc + 1 < Tc) ? ccS[tc + 1] : make_int2(0, 0);
                float cv = (l < 50) ? cring[tc & 3][erow] : 0.f;
                acc0 = 0.f; acc1 = 0.f; acc2 = 0.f; acc3 = 0.f;

                if (tc >= 1 && li == Lc + tc - 1) {
                    // fast path: left = previous node
                    const float* hrow = &hist[(size_t)(tc - 1) * Ec];
                    float vo = 0.f;
                    if (wv == 0 && l < 50) vo = hrow[50 + l];   // wave0 needs other half
                    // 16 uniform quads, k = 0..63
                    float4 q0  = *(const float4*)(hrow +  0);
                    float4 q1  = *(const float4*)(hrow +  4);
                    float4 q2  = *(const float4*)(hrow +  8);
                    float4 q3  = *(const float4*)(hrow + 12);
                    float4 q4  = *(const float4*)(hrow + 16);
                    float4 q5  = *(const float4*)(hrow + 20);
                    float4 q6  = *(const float4*)(hrow + 24);
                    float4 q7  = *(const float4*)(hrow + 28);
                    float4 q8  = *(const float4*)(hrow + 32);
                    float4 q9  = *(const float4*)(hrow + 36);
                    float4 q10 = *(const float4*)(hrow + 40);
                    float4 q11 = *(const float4*)(hrow + 44);
                    float4 q12 = *(const float4*)(hrow + 48);
                    float4 q13 = *(const float4*)(hrow + 52);
                    float4 q14 = *(const float4*)(hrow + 56);
                    float4 q15 = *(const float4*)(hrow + 60);
                    // readlane tail k=64..99 (VALU pipe; overlaps quad DS latency)
                    if (wv == 0) { RLPART(SRC0) } else { RLPART(SRC1) }
                    // quad fmas (VGPR x VGPR)
                    QFMA(q0, 0, 1, 2, 3)     QFMA(q1, 4, 5, 6, 7)
                    QFMA(q2, 8, 9, 10, 11)   QFMA(q3, 12, 13, 14, 15)
                    QFMA(q4, 16, 17, 18, 19) QFMA(q5, 20, 21, 22, 23)
                    QFMA(q6, 24, 25, 26, 27) QFMA(q7, 28, 29, 30, 31)
                    QFMA(q8, 32, 33, 34, 35) QFMA(q9, 36, 37, 38, 39)
                    QFMA(q10, 40, 41, 42, 43) QFMA(q11, 44, 45, 46, 47)
                    QFMA(q12, 48, 49, 50, 51) QFMA(q13, 52, 53, 54, 55)
                    QFMA(q14, 56, 57, 58, 59) QFMA(q15, 60, 61, 62, 63)
                } else if (li >= Lc) {
                    acc0 += slow_dot(&hist[(size_t)min(li - Lc, Tc - 1) * Ec],
                                     W1 + (size_t)erow * W1cols);
                } else {
                    const int tl = __builtin_amdgcn_readfirstlane(tokLS[tc]);
                    acc0 += slow_dot(emb + (size_t)max(tl, 0) * Ec,
                                     W1 + (size_t)erow * W1cols);
                }
                if (ri >= Lc)
                    acc0 += slow_dot(&hist[(size_t)min(ri - Lc, Tc - 1) * Ec],
                                     W1 + (size_t)erow * W1cols + Ec);

                const float x = ((acc0 + acc1) + (acc2 + acc3)) + cv;
                const float u = __expf(2.f * x);
                vh = 1.f - 2.f / (u + 1.f);          // tanh, exact identity
                if (l < 50) hist[(size_t)tc * Ec + erow] = vh;
                cc = ccn;
            }
        }
        // one barrier per tick; vmcnt NOT drained (producer loads stay in flight)
        asm volatile("s_waitcnt lgkmcnt(0)\n\ts_barrier" ::: "memory");
    }

    // ---- out[b] = sigmoid(W2 . h_254 + b2) ----
    if (cons) {
        float p = (l < 50) ? w2e * vh : 0.f;
        #pragma unroll
        for (int off = 32; off > 0; off >>= 1) p += __shfl_down(p, off, 64);
        if (l == 0) red[wv] = p;
    }
    __syncthreads();
    if (tid == 0) out[b] = 1.f / (1.f + __expf(-(red[0] + red[1] + b2v)));
}

extern "C" void kernel_launch(void* const* d_in, const int* in_sizes, int n_in,
                              void* d_out, int out_size, void* d_ws, size_t ws_size,
                              hipStream_t stream) {
    const int*   token_ids  = (const int*)  d_in[0];
    const int*   comp_left  = (const int*)  d_in[1];
    const int*   comp_right = (const int*)  d_in[2];
    const float* emb        = (const float*)d_in[3];
    const float* W1         = (const float*)d_in[4];
    const float* b1         = (const float*)d_in[5];
    const float* W2         = (const float*)d_in[6];
    const float* b2         = (const float*)d_in[7];
    float*       out        = (float*)d_out;

    fused<<<Bc, 512, 0, stream>>>(token_ids, comp_left, comp_right,
                                  emb, W1, b1, W2, b2, out);
}